// Round 7
// baseline (1348.397 us; speedup 1.0000x reference)
//
#include <hip/hip_runtime.h>
#include <hip/hip_cooperative_groups.h>
#include <math.h>

namespace cg = cooperative_groups;

#define MM 1024      // checks
#define NN 2048      // vars
#define BB 128       // batch
#define TT 5         // iterations
#define EE 6144      // edges

typedef __bf16 bf16x8 __attribute__((ext_vector_type(8)));
typedef __bf16 bf16x4 __attribute__((ext_vector_type(4)));
typedef short  s16x4  __attribute__((ext_vector_type(4)));
typedef float  f32x4  __attribute__((ext_vector_type(4)));
typedef unsigned int u32x4 __attribute__((ext_vector_type(4)));

typedef const __attribute__((address_space(1))) void* gas_p;
typedef __attribute__((address_space(3))) void* las_p;

// prepped weight sizes (bf16 elements)
// chk L2 layout: per mt (3): 6 interleaved ks-pairs (512 el) + ks12 (256 el) = 3328 el
#define CHK_W_ELEMS 22272   // 24 x32-frags (512) + 3*3328 L2
#define CHK_L2_OFF  12288
// var L2 layout: per mt (2): 3 interleaved ks-pairs (512) + ks6 (256) = 1792 el
#define VAR_W_ELEMS 7168
#define VAR_L2_OFF  3584

// Abramowitz-Stegun 7.1.26 erf (|eps| < 1.5e-7)
__device__ __forceinline__ float gelu_fast(float x) {
    float xe = x * 0.70710678118654752f;
    float ax = fabsf(xe);
    float t  = __builtin_amdgcn_rcpf(1.0f + 0.3275911f * ax);
    float p  = t * (0.254829592f + t * (-0.284496736f + t * (1.421413741f +
               t * (-1.453152027f + t * 1.061405429f))));
    float er = 1.0f - p * __expf(-xe * xe);
    er = copysignf(er, xe);
    return 0.5f * x * (1.0f + er);
}

__device__ __forceinline__ f32x4 mfma16(bf16x4 a, bf16x4 b, f32x4 c) {
#if __has_builtin(__builtin_amdgcn_mfma_f32_16x16x16bf16_1k)
    return __builtin_amdgcn_mfma_f32_16x16x16bf16_1k(
        __builtin_bit_cast(s16x4, a), __builtin_bit_cast(s16x4, b), c, 0, 0, 0);
#else
    f32x4 d;
    asm volatile("v_mfma_f32_16x16x16_bf16 %0, %1, %2, %3\n\ts_nop 4"
                 : "=v"(d) : "v"(a), "v"(b), "v"(c));
    return d;
#endif
}

// wave-private LDS fence (DS ops in-order per wave)
__device__ __forceinline__ void wave_lds_fence() {
    asm volatile("s_waitcnt lgkmcnt(0)" ::: "memory");
}

// ---------------------------------------------------------------------------
// prep (r6, unchanged): barrier-free wave-private packing, split so neither
// dispatch exceeds the loop kernels.
// ---------------------------------------------------------------------------
__global__ __launch_bounds__(256, 6)
void prep_chk(const float* __restrict__ cw1, const float* __restrict__ cb1,
              const float* __restrict__ cw2, const float* __restrict__ cb2,
              __bf16* __restrict__ wchk)
{
    const int tid = threadIdx.x;
    const int w = tid >> 6, l = tid & 63, q = l >> 4, c = l & 15;

    __shared__ __align__(16) float s[6656];
    float* sw = s + w * 1664;

    const int m = blockIdx.x;
    const float* w1p = cw1 + (size_t)m * 9216;
    const float* w2p = cw2 + (size_t)m * 9216;
    __bf16* dst = wchk + (size_t)m * CHK_W_ELEMS;

    #pragma unroll
    for (int i0 = 0; i0 < 6; ++i0) {
        int i = i0 * 64 + l;
        int r = i / 12, c4 = i % 12;
        float4 v = *(const float4*)(w1p + r * 192 + w * 48 + c4 * 4);
        *(float2*)(sw + r * 50 + c4 * 4)     = make_float2(v.x, v.y);
        *(float2*)(sw + r * 50 + c4 * 4 + 2) = make_float2(v.z, v.w);
    }
    wave_lds_fence();
    #pragma unroll
    for (int d = 0; d < 3; ++d) {
        int mt = 3 * w + d;
        bf16x8 v;
        #pragma unroll
        for (int j = 0; j < 8; ++j)
            v[j] = (__bf16)sw[(q * 8 + j) * 50 + d * 16 + c];
        *(bf16x8*)(dst + (mt * 2) * 512 + l * 8) = v;
    }
    wave_lds_fence();

    #pragma unroll
    for (int i0 = 0; i0 < 4; ++i0) {
        int i = i0 * 64 + l;
        if (i < 204) {
            int r = i / 12, c4 = i % 12;
            const float* src = (r < 16)
                ? (w1p + (32 + r) * 192 + w * 48 + c4 * 4)
                : (cb1 + (size_t)m * 192 + w * 48 + c4 * 4);
            float4 v = *(const float4*)src;
            *(float2*)(sw + r * 50 + c4 * 4)     = make_float2(v.x, v.y);
            *(float2*)(sw + r * 50 + c4 * 4 + 2) = make_float2(v.z, v.w);
        }
    }
    wave_lds_fence();
    #pragma unroll
    for (int d = 0; d < 3; ++d) {
        int mt = 3 * w + d;
        bf16x8 v;
        #pragma unroll
        for (int j = 0; j < 8; ++j) {
            int lr = q * 8 + j;
            float wv = sw[lr * 50 + d * 16 + c];
            v[j] = (__bf16)((lr <= 16) ? wv : 0.0f);
        }
        *(bf16x8*)(dst + (mt * 2 + 1) * 512 + l * 8) = v;
    }
    wave_lds_fence();

    for (int t = w; t < 10; t += 4) {
        if (t < 9) {
            const int kb = t / 3, mt = t - kb * 3;
            #pragma unroll
            for (int i0 = 0; i0 < 4; ++i0) {
                int i = i0 * 64 + l;
                int r = i >> 2, c4 = i & 3;
                float4 v = *(const float4*)(w2p + (kb * 64 + r) * 48 + mt * 16 + c4 * 4);
                *(float4*)(sw + r * 20 + c4 * 4) = v;
            }
            wave_lds_fence();
            #pragma unroll
            for (int kk = 0; kk < 4; ++kk) {
                const int ks = kb * 4 + kk;
                const int kp = ks >> 1, half = ks & 1;
                bf16x4 v;
                #pragma unroll
                for (int r = 0; r < 4; ++r)
                    v[r] = (__bf16)sw[(kk * 16 + q * 4 + r) * 20 + c];
                *(bf16x4*)(dst + CHK_L2_OFF + mt * 3328 + kp * 512 + l * 8 + half * 4) = v;
            }
            wave_lds_fence();
        } else {
            #pragma unroll
            for (int mt = 0; mt < 3; ++mt) {
                bf16x4 v;
                #pragma unroll
                for (int r = 0; r < 4; ++r) v[r] = (__bf16)0.0f;
                if (q == 0) v[0] = (__bf16)cb2[(size_t)m * 48 + mt * 16 + c];
                *(bf16x4*)(dst + CHK_L2_OFF + mt * 3328 + 3072 + l * 4) = v;
            }
        }
    }
}

#define PREP_OTHER_GRID (2048 + 512 + 3072)

__global__ __launch_bounds__(256, 6)
void prep_other(const float* __restrict__ vw1, const float* __restrict__ vb1,
                const float* __restrict__ vw2, const float* __restrict__ vb2,
                const int* __restrict__ synd, const float* __restrict__ prior,
                __bf16* __restrict__ wvar, float* __restrict__ sgnT,
                __bf16* __restrict__ v2c)
{
    const int bid = blockIdx.x;
    const int tid = threadIdx.x;
    const int w = tid >> 6, l = tid & 63, q = l >> 4, c = l & 15;

    __shared__ __align__(16) float s[6656];
    float* sw = s + w * 1664;

    if (bid < 2048) {
        const int nv = bid;
        const float* w1p = vw1 + (size_t)nv * 2500;
        const float* w2p = vw2 + (size_t)nv * 2500;
        __bf16* dst = wvar + (size_t)nv * VAR_W_ELEMS;

        if (w < 3) {
            #pragma unroll
            for (int i0 = 0; i0 < 4; ++i0) {
                int i = i0 * 64 + l;
                if (i < 208) {
                    int r = i >> 3, c4 = i & 7;
                    const float* src = (r < 25)
                        ? (w1p + r * 100 + w * 32 + c4 * 4)
                        : (vb1 + (size_t)nv * 100 + w * 32 + c4 * 4);
                    float4 v = *(const float4*)src;
                    *(float2*)(sw + r * 34 + c4 * 4)     = make_float2(v.x, v.y);
                    *(float2*)(sw + r * 34 + c4 * 4 + 2) = make_float2(v.z, v.w);
                }
            }
        } else {
            if (l < 26) {
                int r = l;
                const float* src = (r < 25) ? (w1p + r * 100 + 96)
                                            : (vb1 + (size_t)nv * 100 + 96);
                float4 v = *(const float4*)src;
                *(float2*)(sw + r * 34)     = make_float2(v.x, v.y);
                *(float2*)(sw + r * 34 + 2) = make_float2(v.z, v.w);
            }
        }
        wave_lds_fence();
        {
            const int nmt = (w < 3) ? 2 : 1;
            #pragma unroll
            for (int d = 0; d < 2; ++d) {
                if (d < nmt) {
                    const int mt = (w < 3) ? (2 * w + d) : 6;
                    const int h = mt * 16 + c;
                    bf16x8 v;
                    #pragma unroll
                    for (int j = 0; j < 8; ++j) {
                        int k = q * 8 + j;
                        float wv = sw[k * 34 + d * 16 + c];
                        v[j] = (__bf16)((h < 100 && k <= 25) ? wv : 0.0f);
                    }
                    *(bf16x8*)(dst + mt * 512 + l * 8) = v;
                }
            }
        }
        wave_lds_fence();

        if (w < 3) {
            #pragma unroll
            for (int i0 = 0; i0 < 4; ++i0) {
                int i = i0 * 64 + l;
                if (i < 200)
                    *(float4*)(sw + i * 4) = *(const float4*)(w2p + 800 * w + i * 4);
            }
        } else {
            if (l < 25) *(float4*)(sw + l * 4) = *(const float4*)(w2p + 2400 + l * 4);
            if (l < 25) sw[100 + l] = vb2[(size_t)nv * 25 + l];
        }
        wave_lds_fence();
        {
            const int nks = (w < 3) ? 2 : 1;
            #pragma unroll
            for (int kk = 0; kk < 2; ++kk) {
                if (kk < nks) {
                    #pragma unroll
                    for (int mt = 0; mt < 2; ++mt) {
                        const int o = mt * 16 + c;
                        bf16x4 v;
                        #pragma unroll
                        for (int r = 0; r < 4; ++r) {
                            float x;
                            if (w < 3) {
                                int lk = kk * 16 + q * 4 + r;
                                float wv = sw[lk * 25 + o];
                                x = (o < 25) ? wv : 0.0f;
                            } else {
                                int lk = q * 4 + r;
                                float wv = sw[lk * 25 + o];
                                x = (o < 25 && lk <= 4) ? wv : 0.0f;
                            }
                            v[r] = (__bf16)x;
                        }
                        if (w < 3)
                            *(bf16x4*)(dst + VAR_L2_OFF + mt * 1792 + w * 512 + l * 8 + kk * 4) = v;
                        else
                            *(bf16x4*)(dst + VAR_L2_OFF + mt * 1792 + 1536 + l * 4) = v;
                    }
                }
            }
        }
    } else if (bid < 2560) {
        int idx = (bid - 2048) * 256 + tid;
        int m = idx >> 7, b = idx & 127;
        sgnT[idx] = (float)(1 - 2 * synd[(size_t)b * MM + m]);
    } else {
        int idx = (bid - 2560) * 256 + tid;
        int e = idx >> 7;
        bf16x8 v;
        #pragma unroll
        for (int j = 0; j < 8; ++j) v[j] = (__bf16)0.0f;
        v[0] = (__bf16)prior[e / 3];
        *(bf16x8*)(v2c + (size_t)idx * 8) = v;
    }
}

// ---------------------------------------------------------------------------
// shared compute helpers
// ---------------------------------------------------------------------------
__device__ __forceinline__ void chk_layer1(const __bf16* wlds, int l,
                                           bf16x8 b0, bf16x8 b1, f32x4* acc)
{
    #pragma unroll
    for (int mt = 0; mt < 12; ++mt) {
        bf16x8 a0 = *(const bf16x8*)(wlds + (mt * 2 + 0) * 512 + l * 8);
        bf16x8 a1 = *(const bf16x8*)(wlds + (mt * 2 + 1) * 512 + l * 8);
        f32x4 z = {0.f, 0.f, 0.f, 0.f};
        z = __builtin_amdgcn_mfma_f32_16x16x32_bf16(a0, b0, z, 0, 0, 0);
        z = __builtin_amdgcn_mfma_f32_16x16x32_bf16(a1, b1, z, 0, 0, 0);
        acc[mt] = z;
    }
}

__device__ __forceinline__ void chk_layer2(const __bf16* wlds, int l, int q,
                                           const f32x4* acc, f32x4* acc2)
{
    #pragma unroll
    for (int mt = 0; mt < 3; ++mt) acc2[mt] = (f32x4){0.f, 0.f, 0.f, 0.f};
    #pragma unroll
    for (int kp = 0; kp < 6; ++kp) {
        bf16x4 bf0, bf1;
        #pragma unroll
        for (int r = 0; r < 4; ++r) bf0[r] = (__bf16)gelu_fast(acc[2 * kp][r]);
        #pragma unroll
        for (int r = 0; r < 4; ++r) bf1[r] = (__bf16)gelu_fast(acc[2 * kp + 1][r]);
        #pragma unroll
        for (int mt = 0; mt < 3; ++mt) {
            bf16x8 a8 = *(const bf16x8*)(wlds + CHK_L2_OFF + mt * 3328 + kp * 512 + l * 8);
            bf16x4 alo = {a8[0], a8[1], a8[2], a8[3]};
            bf16x4 ahi = {a8[4], a8[5], a8[6], a8[7]};
            acc2[mt] = mfma16(alo, bf0, acc2[mt]);
            acc2[mt] = mfma16(ahi, bf1, acc2[mt]);
        }
    }
    bf16x4 bfb;
    #pragma unroll
    for (int r = 0; r < 4; ++r) bfb[r] = (__bf16)0.0f;
    if (q == 0) bfb[0] = (__bf16)1.0f;
    #pragma unroll
    for (int mt = 0; mt < 3; ++mt) {
        bf16x4 af = *(const bf16x4*)(wlds + CHK_L2_OFF + mt * 3328 + 3072 + l * 4);
        acc2[mt] = mfma16(af, bfb, acc2[mt]);
    }
}

#define CPITCH 58
#define VPITCH 26

// one check-MLP task (one m): prefetch -> stage -> two-phase vmcnt -> compute
__device__ __forceinline__ void chk_task(
    int m, int tid, int w, int l, int q, int c,
    const __bf16* __restrict__ wchk, const float* __restrict__ sgnT,
    const int* __restrict__ v2c_gather, const __bf16* __restrict__ v2c,
    __bf16* __restrict__ c2v, __bf16* wlds, __bf16* myy)
{
    const int e0 = v2c_gather[m * 6 + q];
    const int e1 = (q < 2) ? v2c_gather[m * 6 + 4 + q] : 0;

    bf16x8 bA[2], bB[2];
    float sg[2];
    #pragma unroll
    for (int t2 = 0; t2 < 2; ++t2) {
        const int bt = t2 * 64 + w * 16;
        bA[t2] = *(const bf16x8*)(v2c + ((size_t)e0 * BB + bt + c) * 8);
        bf16x8 bb;
        #pragma unroll
        for (int j = 0; j < 8; ++j) bb[j] = (__bf16)0.0f;
        if (q < 2)       bb = *(const bf16x8*)(v2c + ((size_t)e1 * BB + bt + c) * 8);
        else if (q == 2) bb[0] = (__bf16)1.0f;
        bB[t2] = bb;
        sg[t2] = sgnT[m * BB + bt + c];
    }

    {
        const __bf16* src = wchk + (size_t)m * CHK_W_ELEMS;
        #pragma unroll
        for (int r = 0; r < 10; ++r)
            __builtin_amdgcn_global_load_lds(
                (gas_p)(src + (r * 256 + tid) * 8),
                (las_p)(wlds + (r * 256 + tid) * 8), 16, 0, 0);
        if (tid < 224)
            __builtin_amdgcn_global_load_lds(
                (gas_p)(src + (2560 + tid) * 8),
                (las_p)(wlds + (2560 + tid) * 8), 16, 0, 0);
    }
    __builtin_amdgcn_sched_barrier(0);
    asm volatile("s_waitcnt vmcnt(5)" ::: "memory");   // L1 rounds 0-5 landed
    __syncthreads();

    f32x4 acc[12];
    chk_layer1(wlds, l, bA[0], bB[0], acc);

    __builtin_amdgcn_sched_barrier(0);
    asm volatile("s_waitcnt vmcnt(0)" ::: "memory");   // L2 rounds landed
    __syncthreads();

    #pragma unroll
    for (int t2 = 0; t2 < 2; ++t2) {
        if (t2 == 1) chk_layer1(wlds, l, bA[1], bB[1], acc);
        const int bt = t2 * 64 + w * 16;

        f32x4 acc2[3];
        chk_layer2(wlds, l, q, acc, acc2);

        #pragma unroll
        for (int mt = 0; mt < 3; ++mt)
            #pragma unroll
            for (int r = 0; r < 4; ++r)
                myy[c * CPITCH + mt * 16 + q * 4 + r] = (__bf16)(acc2[mt][r] * sg[t2]);
        wave_lds_fence();

        {
            int s = l >> 4, row = l & 15;
            u32x4 vv = *(const u32x4*)(myy + row * CPITCH + s * 8);
            *(u32x4*)(c2v + ((size_t)(m * 6 + s) * BB + bt + row) * 8) = vv;
            if (l < 32) {
                int s2 = 4 + (l >> 4), row2 = l & 15;
                u32x4 v2 = *(const u32x4*)(myy + row2 * CPITCH + s2 * 8);
                *(u32x4*)(c2v + ((size_t)(m * 6 + s2) * BB + bt + row2) * 8) = v2;
            }
        }
        wave_lds_fence();
    }
    __syncthreads();   // all waves done with wlds before it is restaged
}

__device__ __forceinline__ void var_stage(const __bf16* __restrict__ wvar,
                                          int nv, int tid, __bf16* buf)
{
    const __bf16* src = wvar + (size_t)nv * VAR_W_ELEMS;
    #pragma unroll
    for (int r = 0; r < 3; ++r)
        __builtin_amdgcn_global_load_lds(
            (gas_p)(src + (r * 256 + tid) * 8),
            (las_p)(buf + (r * 256 + tid) * 8), 16, 0, 0);
    if (tid < 128)
        __builtin_amdgcn_global_load_lds(
            (gas_p)(src + (768 + tid) * 8),
            (las_p)(buf + (768 + tid) * 8), 16, 0, 0);
}

// ---------------------------------------------------------------------------
// loop_kernel (r7): the entire T-loop as ONE cooperative dispatch.
// 512 blocks x 256 threads, 3/CU capacity (LDS 50.75 KB) >= 512 co-resident.
// Per iteration: chk phase (2 m's/block, r4 two-phase vmcnt staging) ->
// grid.sync() -> var phase (4 nv's/block, ping-pong staged: stage j+1 issued
// AFTER task-j b-frag loads so in-order vmcnt keeps it in flight under
// compute) -> grid.sync(). Eliminates 10 launch gaps + both round tails.
// ---------------------------------------------------------------------------
__global__ __launch_bounds__(256, 3)
void loop_kernel(const __bf16* __restrict__ wchk, const __bf16* __restrict__ wvar,
                 const float* __restrict__ sgnT,
                 const int* __restrict__ v2c_gather, const int* __restrict__ c2v_gather,
                 const float* __restrict__ prior,
                 __bf16* __restrict__ v2c, __bf16* __restrict__ c2v,
                 float* __restrict__ out)
{
    cg::grid_group grid = cg::this_grid();
    const int bid = blockIdx.x;
    const int tid = threadIdx.x;
    const int w = tid >> 6, l = tid & 63, q = l >> 4, c = l & 15;

    __shared__ __align__(16) __bf16 wlds[CHK_W_ELEMS];      // 43.5 KB
    __shared__ __align__(16) __bf16 ytile[4 * 16 * CPITCH]; // 7.25 KB

    __bf16* wv0 = wlds;                  // var ping buffer (14.3 KB)
    __bf16* wv1 = wlds + VAR_W_ELEMS;    // var pong buffer (fits in chk alloc)
    __bf16* myyC = ytile + w * 16 * CPITCH;
    __bf16* myyV = ytile + w * 16 * VPITCH;

    for (int t = 0; t < TT; ++t) {
        // ================= chk phase: m = bid*2 + i =================
        #pragma unroll 1
        for (int i = 0; i < 2; ++i)
            chk_task(bid * 2 + i, tid, w, l, q, c,
                     wchk, sgnT, v2c_gather, v2c, c2v, wlds, myyC);

        __threadfence();
        grid.sync();

        // ================= var phase: nv = bid*4 + j =================
        const int last = (t == TT - 1);
        int eps[4];
        float prs[4];
        #pragma unroll
        for (int jj = 0; jj < 4; ++jj) {
            int nvq = bid * 4 + jj;
            eps[jj] = (q < 3) ? c2v_gather[nvq * 3 + q] : 0;
            prs[jj] = prior[nvq];
        }

        var_stage(wvar, bid * 4, tid, wv0);

        #pragma unroll
        for (int j = 0; j < 4; ++j) {
            const int nv = bid * 4 + j;
            __bf16* buf = (j & 1) ? wv1 : wv0;

            __builtin_amdgcn_sched_barrier(0);
            asm volatile("s_waitcnt vmcnt(0)" ::: "memory");  // buf j landed
            __syncthreads();   // all waves: buf ready AND done with buf j-1

            // b-frag loads for task j (issued BEFORE stage j+1 -> waiting on
            // them never drains the younger stage ops)
            bf16x8 bp[2];
            #pragma unroll
            for (int t2 = 0; t2 < 2; ++t2) {
                const int bt = t2 * 64 + w * 16;
                bf16x8 bb;
                #pragma unroll
                for (int jj = 0; jj < 8; ++jj) bb[jj] = (__bf16)0.0f;
                if (q < 3) bb = *(const bf16x8*)(c2v + ((size_t)eps[j] * BB + bt + c) * 8);
                else { bb[0] = (__bf16)prs[j]; bb[1] = (__bf16)1.0f; }
                bp[t2] = bb;
            }
            __builtin_amdgcn_sched_barrier(0);
            if (j < 3) var_stage(wvar, nv + 1, tid, (j & 1) ? wv0 : wv1);

            #pragma unroll
            for (int t2 = 0; t2 < 2; ++t2) {
                const int bt = t2 * 64 + w * 16;
                const bf16x8 b0 = bp[t2];

                f32x4 acc[7];
                #pragma unroll
                for (int mt = 0; mt < 7; ++mt) {
                    bf16x8 a0 = *(const bf16x8*)(buf + mt * 512 + l * 8);
                    f32x4 z = {0.f, 0.f, 0.f, 0.f};
                    acc[mt] = __builtin_amdgcn_mfma_f32_16x16x32_bf16(a0, b0, z, 0, 0, 0);
                }

                f32x4 acc2[2];
                acc2[0] = (f32x4){0.f, 0.f, 0.f, 0.f};
                acc2[1] = (f32x4){0.f, 0.f, 0.f, 0.f};
                #pragma unroll
                for (int kp = 0; kp < 3; ++kp) {
                    bf16x4 bf0, bf1;
                    #pragma unroll
                    for (int r = 0; r < 4; ++r) bf0[r] = (__bf16)gelu_fast(acc[2 * kp][r]);
                    #pragma unroll
                    for (int r = 0; r < 4; ++r) bf1[r] = (__bf16)gelu_fast(acc[2 * kp + 1][r]);
                    #pragma unroll
                    for (int mt = 0; mt < 2; ++mt) {
                        bf16x8 a8 = *(const bf16x8*)(buf + VAR_L2_OFF + mt * 1792 + kp * 512 + l * 8);
                        bf16x4 alo = {a8[0], a8[1], a8[2], a8[3]};
                        bf16x4 ahi = {a8[4], a8[5], a8[6], a8[7]};
                        acc2[mt] = mfma16(alo, bf0, acc2[mt]);
                        acc2[mt] = mfma16(ahi, bf1, acc2[mt]);
                    }
                }
                {
                    bf16x4 bf6;
                    #pragma unroll
                    for (int r = 0; r < 4; ++r) bf6[r] = (__bf16)gelu_fast(acc[6][r]);
                    if (q == 1) bf6[0] = (__bf16)1.0f;
                    #pragma unroll
                    for (int mt = 0; mt < 2; ++mt) {
                        bf16x4 af = *(const bf16x4*)(buf + VAR_L2_OFF + mt * 1792 + 1536 + l * 4);
                        acc2[mt] = mfma16(af, bf6, acc2[mt]);
                    }
                }

                #pragma unroll
                for (int r = 0; r < 4; ++r)
                    myyV[c * VPITCH + q * 4 + r] = (__bf16)acc2[0][r];
                if (q < 2)
                    #pragma unroll
                    for (int r = 0; r < 4; ++r)
                        myyV[c * VPITCH + 16 + q * 4 + r] = (__bf16)acc2[1][r];
                if (q == 2) out[(size_t)t * BB * NN + (size_t)(bt + c) * NN + nv] = acc2[1][0];
                wave_lds_fence();

                if (!last && l < 48) {
                    int s = l >> 4, row = l & 15;
                    u32x4 vv = *(const u32x4*)(myyV + row * VPITCH + s * 8);
                    *(u32x4*)(v2c + ((size_t)(nv * 3 + s) * BB + bt + row) * 8) = vv;
                }
                wave_lds_fence();
            }
        }
        __syncthreads();   // ytile/wlds quiesced before next phase

        if (t != TT - 1) {
            __threadfence();
            grid.sync();
        }
    }
}

// ---------------------------------------------------------------------------
// Fallback per-iteration kernels (r6 structure) — used only if cooperative
// launch is unavailable (e.g. capture restriction).
// ---------------------------------------------------------------------------
__global__ __launch_bounds__(256, 3)
void chk_kernel(const __bf16* __restrict__ wchk,
                const float* __restrict__ sgnT,
                const int* __restrict__ v2c_gather,
                const __bf16* __restrict__ v2c, __bf16* __restrict__ c2v)
{
    const int m = blockIdx.x;
    const int tid = threadIdx.x;
    const int w = tid >> 6, l = tid & 63, q = l >> 4, c = l & 15;

    __shared__ __align__(16) __bf16 wlds[CHK_W_ELEMS];
    __shared__ __align__(16) __bf16 ytile[4 * 16 * CPITCH];

    chk_task(m, tid, w, l, q, c, wchk, sgnT, v2c_gather, v2c, c2v,
             wlds, ytile + w * 16 * CPITCH);
}

__global__ __launch_bounds__(256, 5)
void var_kernel(const __bf16* __restrict__ wvar,
                const int* __restrict__ c2v_gather, const float* __restrict__ prior,
                const __bf16* __restrict__ c2v, __bf16* __restrict__ v2c,
                float* __restrict__ llr_out, int last)
{
    const int nv = blockIdx.x;
    const int tid = threadIdx.x;
    const int w = tid >> 6, l = tid & 63, q = l >> 4, c = l & 15;

    __shared__ __align__(16) __bf16 wlds[VAR_W_ELEMS];
    __shared__ __align__(16) __bf16 ytile[4 * 16 * VPITCH];

    const int ep = (q < 3) ? c2v_gather[nv * 3 + q] : 0;
    const __bf16 prbf = (__bf16)prior[nv];

    bf16x8 bp[2];
    #pragma unroll
    for (int t2 = 0; t2 < 2; ++t2) {
        const int bt = t2 * 64 + w * 16;
        bf16x8 bb;
        #pragma unroll
        for (int j = 0; j < 8; ++j) bb[j] = (__bf16)0.0f;
        if (q < 3) bb = *(const bf16x8*)(c2v + ((size_t)ep * BB + bt + c) * 8);
        else { bb[0] = prbf; bb[1] = (__bf16)1.0f; }
        bp[t2] = bb;
    }

    var_stage(wvar, nv, tid, wlds);
    __builtin_amdgcn_sched_barrier(0);
    asm volatile("s_waitcnt vmcnt(0)" ::: "memory");
    __syncthreads();

    __bf16* myy = ytile + w * 16 * VPITCH;

    #pragma unroll
    for (int t2 = 0; t2 < 2; ++t2) {
        const int bt = t2 * 64 + w * 16;
        const bf16x8 b0 = bp[t2];

        f32x4 acc[7];
        #pragma unroll
        for (int mt = 0; mt < 7; ++mt) {
            bf16x8 a0 = *(const bf16x8*)(wlds + mt * 512 + l * 8);
            f32x4 z = {0.f, 0.f, 0.f, 0.f};
            acc[mt] = __builtin_amdgcn_mfma_f32_16x16x32_bf16(a0, b0, z, 0, 0, 0);
        }

        f32x4 acc2[2];
        acc2[0] = (f32x4){0.f, 0.f, 0.f, 0.f};
        acc2[1] = (f32x4){0.f, 0.f, 0.f, 0.f};
        #pragma unroll
        for (int kp = 0; kp < 3; ++kp) {
            bf16x4 bf0, bf1;
            #pragma unroll
            for (int r = 0; r < 4; ++r) bf0[r] = (__bf16)gelu_fast(acc[2 * kp][r]);
            #pragma unroll
            for (int r = 0; r < 4; ++r) bf1[r] = (__bf16)gelu_fast(acc[2 * kp + 1][r]);
            #pragma unroll
            for (int mt = 0; mt < 2; ++mt) {
                bf16x8 a8 = *(const bf16x8*)(wlds + VAR_L2_OFF + mt * 1792 + kp * 512 + l * 8);
                bf16x4 alo = {a8[0], a8[1], a8[2], a8[3]};
                bf16x4 ahi = {a8[4], a8[5], a8[6], a8[7]};
                acc2[mt] = mfma16(alo, bf0, acc2[mt]);
                acc2[mt] = mfma16(ahi, bf1, acc2[mt]);
            }
        }
        {
            bf16x4 bf6;
            #pragma unroll
            for (int r = 0; r < 4; ++r) bf6[r] = (__bf16)gelu_fast(acc[6][r]);
            if (q == 1) bf6[0] = (__bf16)1.0f;
            #pragma unroll
            for (int mt = 0; mt < 2; ++mt) {
                bf16x4 af = *(const bf16x4*)(wlds + VAR_L2_OFF + mt * 1792 + 1536 + l * 4);
                acc2[mt] = mfma16(af, bf6, acc2[mt]);
            }
        }

        #pragma unroll
        for (int r = 0; r < 4; ++r)
            myy[c * VPITCH + q * 4 + r] = (__bf16)acc2[0][r];
        if (q < 2)
            #pragma unroll
            for (int r = 0; r < 4; ++r)
                myy[c * VPITCH + 16 + q * 4 + r] = (__bf16)acc2[1][r];
        if (q == 2) llr_out[(size_t)(bt + c) * NN + nv] = acc2[1][0];
        wave_lds_fence();

        if (!last && l < 48) {
            int s = l >> 4, row = l & 15;
            u32x4 vv = *(const u32x4*)(myy + row * VPITCH + s * 8);
            *(u32x4*)(v2c + ((size_t)(nv * 3 + s) * BB + bt + row) * 8) = vv;
        }
        wave_lds_fence();
    }
}

extern "C" void kernel_launch(void* const* d_in, const int* in_sizes, int n_in,
                              void* d_out, int out_size, void* d_ws, size_t ws_size,
                              hipStream_t stream) {
    const int*   syndromes = (const int*)  d_in[0];
    const float* prior_llr = (const float*)d_in[1];
    const float* chk_w1    = (const float*)d_in[2];
    const float* chk_b1    = (const float*)d_in[3];
    const float* chk_w2    = (const float*)d_in[4];
    const float* chk_b2    = (const float*)d_in[5];
    const float* var_w1    = (const float*)d_in[6];
    const float* var_b1    = (const float*)d_in[7];
    const float* var_w2    = (const float*)d_in[8];
    const float* var_b2    = (const float*)d_in[9];
    const int*   c2v_g     = (const int*)  d_in[11];
    const int*   v2c_g     = (const int*)  d_in[12];

    float* out = (float*)d_out;

    __bf16* v2c  = (__bf16*)d_ws;                           // 12.6 MB
    __bf16* c2v  = v2c + (size_t)EE * BB * 8;               // 12.6 MB
    __bf16* wchk = c2v + (size_t)EE * BB * 8;               // 45.6 MB
    __bf16* wvar = wchk + (size_t)MM * CHK_W_ELEMS;         // 29.4 MB
    float*  sgnT = (float*)(wvar + (size_t)NN * VAR_W_ELEMS); // 512 KB

    prep_chk<<<MM, 256, 0, stream>>>(chk_w1, chk_b1, chk_w2, chk_b2, wchk);
    prep_other<<<PREP_OTHER_GRID, 256, 0, stream>>>(var_w1, var_b1, var_w2, var_b2,
                                                    syndromes, prior_llr,
                                                    wvar, sgnT, v2c);

    const __bf16* wchk_c = wchk; const __bf16* wvar_c = wvar;
    const float* sgnT_c = sgnT;
    void* kargs[] = {(void*)&wchk_c, (void*)&wvar_c, (void*)&sgnT_c,
                     (void*)&v2c_g, (void*)&c2v_g, (void*)&prior_llr,
                     (void*)&v2c, (void*)&c2v, (void*)&out};
    hipError_t err = hipLaunchCooperativeKernel(
        reinterpret_cast<const void*>(loop_kernel),
        dim3(512), dim3(256), kargs, 0, stream);

    if (err != hipSuccess) {
        // fallback: proven per-iteration path
        for (int t = 0; t < TT; ++t) {
            chk_kernel<<<MM, 256, 0, stream>>>(wchk, sgnT, v2c_g, v2c, c2v);
            var_kernel<<<NN, 256, 0, stream>>>(wvar, c2v_g, prior_llr, c2v, v2c,
                                               out + (size_t)t * BB * NN,
                                               (t == TT - 1) ? 1 : 0);
        }
    }
}

// Round 8
// 443.357 us; speedup vs baseline: 3.0413x; 3.0413x over previous
//
#include <hip/hip_runtime.h>
#include <math.h>

#define MM 1024      // checks
#define NN 2048      // vars
#define BB 128       // batch
#define TT 5         // iterations
#define EE 6144      // edges

typedef __bf16 bf16x8 __attribute__((ext_vector_type(8)));
typedef __bf16 bf16x4 __attribute__((ext_vector_type(4)));
typedef short  s16x4  __attribute__((ext_vector_type(4)));
typedef float  f32x4  __attribute__((ext_vector_type(4)));
typedef unsigned int u32x4 __attribute__((ext_vector_type(4)));

typedef const __attribute__((address_space(1))) void* gas_p;
typedef __attribute__((address_space(3))) void* las_p;

// prepped weight sizes (bf16 elements)
// chk L2 layout: per mt (3): 6 interleaved ks-pairs (512 el) + ks12 (256 el) = 3328 el
#define CHK_W_ELEMS 22272   // 24 x32-frags (512) + 3*3328 L2
#define CHK_L2_OFF  12288
#define CHK_L1_ELEMS 12288  // staged portion (24 KB = exactly 6 x 4KB rounds)
// var L2 layout: per mt (2): 3 interleaved ks-pairs (512) + ks6 (256) = 1792 el
#define VAR_W_ELEMS 7168
#define VAR_L2_OFF  3584

// Abramowitz-Stegun 7.1.26 erf (|eps| < 1.5e-7)
__device__ __forceinline__ float gelu_fast(float x) {
    float xe = x * 0.70710678118654752f;
    float ax = fabsf(xe);
    float t  = __builtin_amdgcn_rcpf(1.0f + 0.3275911f * ax);
    float p  = t * (0.254829592f + t * (-0.284496736f + t * (1.421413741f +
               t * (-1.453152027f + t * 1.061405429f))));
    float er = 1.0f - p * __expf(-xe * xe);
    er = copysignf(er, xe);
    return 0.5f * x * (1.0f + er);
}

__device__ __forceinline__ f32x4 mfma16(bf16x4 a, bf16x4 b, f32x4 c) {
#if __has_builtin(__builtin_amdgcn_mfma_f32_16x16x16bf16_1k)
    return __builtin_amdgcn_mfma_f32_16x16x16bf16_1k(
        __builtin_bit_cast(s16x4, a), __builtin_bit_cast(s16x4, b), c, 0, 0, 0);
#else
    f32x4 d;
    asm volatile("v_mfma_f32_16x16x16_bf16 %0, %1, %2, %3\n\ts_nop 4"
                 : "=v"(d) : "v"(a), "v"(b), "v"(c));
    return d;
#endif
}

// wave-private LDS fence (DS ops in-order per wave)
__device__ __forceinline__ void wave_lds_fence() {
    asm volatile("s_waitcnt lgkmcnt(0)" ::: "memory");
}

// ---------------------------------------------------------------------------
// prep (r6, unchanged): barrier-free wave-private packing.
// ---------------------------------------------------------------------------
__global__ __launch_bounds__(256, 6)
void prep_chk(const float* __restrict__ cw1, const float* __restrict__ cb1,
              const float* __restrict__ cw2, const float* __restrict__ cb2,
              __bf16* __restrict__ wchk)
{
    const int tid = threadIdx.x;
    const int w = tid >> 6, l = tid & 63, q = l >> 4, c = l & 15;

    __shared__ __align__(16) float s[6656];
    float* sw = s + w * 1664;

    const int m = blockIdx.x;
    const float* w1p = cw1 + (size_t)m * 9216;
    const float* w2p = cw2 + (size_t)m * 9216;
    __bf16* dst = wchk + (size_t)m * CHK_W_ELEMS;

    #pragma unroll
    for (int i0 = 0; i0 < 6; ++i0) {
        int i = i0 * 64 + l;
        int r = i / 12, c4 = i % 12;
        float4 v = *(const float4*)(w1p + r * 192 + w * 48 + c4 * 4);
        *(float2*)(sw + r * 50 + c4 * 4)     = make_float2(v.x, v.y);
        *(float2*)(sw + r * 50 + c4 * 4 + 2) = make_float2(v.z, v.w);
    }
    wave_lds_fence();
    #pragma unroll
    for (int d = 0; d < 3; ++d) {
        int mt = 3 * w + d;
        bf16x8 v;
        #pragma unroll
        for (int j = 0; j < 8; ++j)
            v[j] = (__bf16)sw[(q * 8 + j) * 50 + d * 16 + c];
        *(bf16x8*)(dst + (mt * 2) * 512 + l * 8) = v;
    }
    wave_lds_fence();

    #pragma unroll
    for (int i0 = 0; i0 < 4; ++i0) {
        int i = i0 * 64 + l;
        if (i < 204) {
            int r = i / 12, c4 = i % 12;
            const float* src = (r < 16)
                ? (w1p + (32 + r) * 192 + w * 48 + c4 * 4)
                : (cb1 + (size_t)m * 192 + w * 48 + c4 * 4);
            float4 v = *(const float4*)src;
            *(float2*)(sw + r * 50 + c4 * 4)     = make_float2(v.x, v.y);
            *(float2*)(sw + r * 50 + c4 * 4 + 2) = make_float2(v.z, v.w);
        }
    }
    wave_lds_fence();
    #pragma unroll
    for (int d = 0; d < 3; ++d) {
        int mt = 3 * w + d;
        bf16x8 v;
        #pragma unroll
        for (int j = 0; j < 8; ++j) {
            int lr = q * 8 + j;
            float wv = sw[lr * 50 + d * 16 + c];
            v[j] = (__bf16)((lr <= 16) ? wv : 0.0f);
        }
        *(bf16x8*)(dst + (mt * 2 + 1) * 512 + l * 8) = v;
    }
    wave_lds_fence();

    for (int t = w; t < 10; t += 4) {
        if (t < 9) {
            const int kb = t / 3, mt = t - kb * 3;
            #pragma unroll
            for (int i0 = 0; i0 < 4; ++i0) {
                int i = i0 * 64 + l;
                int r = i >> 2, c4 = i & 3;
                float4 v = *(const float4*)(w2p + (kb * 64 + r) * 48 + mt * 16 + c4 * 4);
                *(float4*)(sw + r * 20 + c4 * 4) = v;
            }
            wave_lds_fence();
            #pragma unroll
            for (int kk = 0; kk < 4; ++kk) {
                const int ks = kb * 4 + kk;
                const int kp = ks >> 1, half = ks & 1;
                bf16x4 v;
                #pragma unroll
                for (int r = 0; r < 4; ++r)
                    v[r] = (__bf16)sw[(kk * 16 + q * 4 + r) * 20 + c];
                *(bf16x4*)(dst + CHK_L2_OFF + mt * 3328 + kp * 512 + l * 8 + half * 4) = v;
            }
            wave_lds_fence();
        } else {
            #pragma unroll
            for (int mt = 0; mt < 3; ++mt) {
                bf16x4 v;
                #pragma unroll
                for (int r = 0; r < 4; ++r) v[r] = (__bf16)0.0f;
                if (q == 0) v[0] = (__bf16)cb2[(size_t)m * 48 + mt * 16 + c];
                *(bf16x4*)(dst + CHK_L2_OFF + mt * 3328 + 3072 + l * 4) = v;
            }
        }
    }
}

#define PREP_OTHER_GRID (2048 + 512 + 3072)

__global__ __launch_bounds__(256, 6)
void prep_other(const float* __restrict__ vw1, const float* __restrict__ vb1,
                const float* __restrict__ vw2, const float* __restrict__ vb2,
                const int* __restrict__ synd, const float* __restrict__ prior,
                __bf16* __restrict__ wvar, float* __restrict__ sgnT,
                __bf16* __restrict__ v2c)
{
    const int bid = blockIdx.x;
    const int tid = threadIdx.x;
    const int w = tid >> 6, l = tid & 63, q = l >> 4, c = l & 15;

    __shared__ __align__(16) float s[6656];
    float* sw = s + w * 1664;

    if (bid < 2048) {
        const int nv = bid;
        const float* w1p = vw1 + (size_t)nv * 2500;
        const float* w2p = vw2 + (size_t)nv * 2500;
        __bf16* dst = wvar + (size_t)nv * VAR_W_ELEMS;

        if (w < 3) {
            #pragma unroll
            for (int i0 = 0; i0 < 4; ++i0) {
                int i = i0 * 64 + l;
                if (i < 208) {
                    int r = i >> 3, c4 = i & 7;
                    const float* src = (r < 25)
                        ? (w1p + r * 100 + w * 32 + c4 * 4)
                        : (vb1 + (size_t)nv * 100 + w * 32 + c4 * 4);
                    float4 v = *(const float4*)src;
                    *(float2*)(sw + r * 34 + c4 * 4)     = make_float2(v.x, v.y);
                    *(float2*)(sw + r * 34 + c4 * 4 + 2) = make_float2(v.z, v.w);
                }
            }
        } else {
            if (l < 26) {
                int r = l;
                const float* src = (r < 25) ? (w1p + r * 100 + 96)
                                            : (vb1 + (size_t)nv * 100 + 96);
                float4 v = *(const float4*)src;
                *(float2*)(sw + r * 34)     = make_float2(v.x, v.y);
                *(float2*)(sw + r * 34 + 2) = make_float2(v.z, v.w);
            }
        }
        wave_lds_fence();
        {
            const int nmt = (w < 3) ? 2 : 1;
            #pragma unroll
            for (int d = 0; d < 2; ++d) {
                if (d < nmt) {
                    const int mt = (w < 3) ? (2 * w + d) : 6;
                    const int h = mt * 16 + c;
                    bf16x8 v;
                    #pragma unroll
                    for (int j = 0; j < 8; ++j) {
                        int k = q * 8 + j;
                        float wv = sw[k * 34 + d * 16 + c];
                        v[j] = (__bf16)((h < 100 && k <= 25) ? wv : 0.0f);
                    }
                    *(bf16x8*)(dst + mt * 512 + l * 8) = v;
                }
            }
        }
        wave_lds_fence();

        if (w < 3) {
            #pragma unroll
            for (int i0 = 0; i0 < 4; ++i0) {
                int i = i0 * 64 + l;
                if (i < 200)
                    *(float4*)(sw + i * 4) = *(const float4*)(w2p + 800 * w + i * 4);
            }
        } else {
            if (l < 25) *(float4*)(sw + l * 4) = *(const float4*)(w2p + 2400 + l * 4);
            if (l < 25) sw[100 + l] = vb2[(size_t)nv * 25 + l];
        }
        wave_lds_fence();
        {
            const int nks = (w < 3) ? 2 : 1;
            #pragma unroll
            for (int kk = 0; kk < 2; ++kk) {
                if (kk < nks) {
                    #pragma unroll
                    for (int mt = 0; mt < 2; ++mt) {
                        const int o = mt * 16 + c;
                        bf16x4 v;
                        #pragma unroll
                        for (int r = 0; r < 4; ++r) {
                            float x;
                            if (w < 3) {
                                int lk = kk * 16 + q * 4 + r;
                                float wv = sw[lk * 25 + o];
                                x = (o < 25) ? wv : 0.0f;
                            } else {
                                int lk = q * 4 + r;
                                float wv = sw[lk * 25 + o];
                                x = (o < 25 && lk <= 4) ? wv : 0.0f;
                            }
                            v[r] = (__bf16)x;
                        }
                        if (w < 3)
                            *(bf16x4*)(dst + VAR_L2_OFF + mt * 1792 + w * 512 + l * 8 + kk * 4) = v;
                        else
                            *(bf16x4*)(dst + VAR_L2_OFF + mt * 1792 + 1536 + l * 4) = v;
                    }
                }
            }
        }
    } else if (bid < 2560) {
        int idx = (bid - 2048) * 256 + tid;
        int m = idx >> 7, b = idx & 127;
        sgnT[idx] = (float)(1 - 2 * synd[(size_t)b * MM + m]);
    } else {
        int idx = (bid - 2560) * 256 + tid;
        int e = idx >> 7;
        bf16x8 v;
        #pragma unroll
        for (int j = 0; j < 8; ++j) v[j] = (__bf16)0.0f;
        v[0] = (__bf16)prior[e / 3];
        *(bf16x8*)(v2c + (size_t)idx * 8) = v;
    }
}

// ---------------------------------------------------------------------------
// compute helpers
// ---------------------------------------------------------------------------
__device__ __forceinline__ void chk_layer1(const __bf16* wlds, int l,
                                           bf16x8 b0, bf16x8 b1, f32x4* acc)
{
    #pragma unroll
    for (int mt = 0; mt < 12; ++mt) {
        bf16x8 a0 = *(const bf16x8*)(wlds + (mt * 2 + 0) * 512 + l * 8);
        bf16x8 a1 = *(const bf16x8*)(wlds + (mt * 2 + 1) * 512 + l * 8);
        f32x4 z = {0.f, 0.f, 0.f, 0.f};
        z = __builtin_amdgcn_mfma_f32_16x16x32_bf16(a0, b0, z, 0, 0, 0);
        z = __builtin_amdgcn_mfma_f32_16x16x32_bf16(a1, b1, z, 0, 0, 0);
        acc[mt] = z;
    }
}

// layer2 A-frags read DIRECTLY from global (linear per lane -> coalesced,
// L2/L3-served; read once per t2). LDS staging gave no cross-wave reuse for
// these (lane l only ever reads offset l*8), so staging only cost occupancy.
__device__ __forceinline__ void chk_layer2g(const __bf16* __restrict__ wl2,
                                            int l, int q,
                                            const f32x4* acc, f32x4* acc2)
{
    #pragma unroll
    for (int mt = 0; mt < 3; ++mt) acc2[mt] = (f32x4){0.f, 0.f, 0.f, 0.f};
    #pragma unroll
    for (int kp = 0; kp < 6; ++kp) {
        bf16x4 bf0, bf1;
        #pragma unroll
        for (int r = 0; r < 4; ++r) bf0[r] = (__bf16)gelu_fast(acc[2 * kp][r]);
        #pragma unroll
        for (int r = 0; r < 4; ++r) bf1[r] = (__bf16)gelu_fast(acc[2 * kp + 1][r]);
        #pragma unroll
        for (int mt = 0; mt < 3; ++mt) {
            bf16x8 a8 = *(const bf16x8*)(wl2 + mt * 3328 + kp * 512 + l * 8);
            bf16x4 alo = {a8[0], a8[1], a8[2], a8[3]};
            bf16x4 ahi = {a8[4], a8[5], a8[6], a8[7]};
            acc2[mt] = mfma16(alo, bf0, acc2[mt]);
            acc2[mt] = mfma16(ahi, bf1, acc2[mt]);
        }
    }
    bf16x4 bfb;
    #pragma unroll
    for (int r = 0; r < 4; ++r) bfb[r] = (__bf16)0.0f;
    if (q == 0) bfb[0] = (__bf16)1.0f;
    #pragma unroll
    for (int mt = 0; mt < 3; ++mt) {
        bf16x4 af = *(const bf16x4*)(wl2 + mt * 3328 + 3072 + l * 4);
        acc2[mt] = mfma16(af, bfb, acc2[mt]);
    }
}

#define CPITCH 58
#define VPITCH 26

// ---------------------------------------------------------------------------
// Check MLP r8: stage ONLY layer-1 frags (24 KB = 6 exact gload_lds rounds);
// layer-2 frags direct-from-global. LDS 32 KB -> 4 blocks/CU, 1024 blocks =
// single scheduling round (no tail). One block barrier total.
// ---------------------------------------------------------------------------
__global__ __launch_bounds__(256, 4)
void chk_kernel(const __bf16* __restrict__ wchk,
                const float* __restrict__ sgnT,
                const int* __restrict__ v2c_gather,
                const __bf16* __restrict__ v2c, __bf16* __restrict__ c2v)
{
    const int m = blockIdx.x;
    const int tid = threadIdx.x;
    const int w = tid >> 6, l = tid & 63, q = l >> 4, c = l & 15;

    __shared__ __align__(16) __bf16 wlds[CHK_L1_ELEMS];     // 24 KB (L1 only)
    __shared__ __align__(16) __bf16 ytile[4 * 16 * CPITCH]; // 7.25 KB

    const __bf16* wl2 = wchk + (size_t)m * CHK_W_ELEMS + CHK_L2_OFF;

    // edge ids first
    const int e0 = v2c_gather[m * 6 + q];
    const int e1 = (q < 2) ? v2c_gather[m * 6 + 4 + q] : 0;

    // prefetch B-frags + signs for both t2 halves
    bf16x8 bA[2], bB[2];
    float sg[2];
    #pragma unroll
    for (int t2 = 0; t2 < 2; ++t2) {
        const int bt = t2 * 64 + w * 16;
        bA[t2] = *(const bf16x8*)(v2c + ((size_t)e0 * BB + bt + c) * 8);
        bf16x8 bb;
        #pragma unroll
        for (int j = 0; j < 8; ++j) bb[j] = (__bf16)0.0f;
        if (q < 2)       bb = *(const bf16x8*)(v2c + ((size_t)e1 * BB + bt + c) * 8);
        else if (q == 2) bb[0] = (__bf16)1.0f;   // bias row k=48
        bB[t2] = bb;
        sg[t2] = sgnT[m * BB + bt + c];
    }

    // stage L1 weights: exactly 6 x 4KB rounds
    {
        const __bf16* src = wchk + (size_t)m * CHK_W_ELEMS;
        #pragma unroll
        for (int r = 0; r < 6; ++r)
            __builtin_amdgcn_global_load_lds(
                (gas_p)(src + (r * 256 + tid) * 8),
                (las_p)(wlds + (r * 256 + tid) * 8), 16, 0, 0);
    }
    __builtin_amdgcn_sched_barrier(0);
    asm volatile("s_waitcnt vmcnt(0)" ::: "memory");
    __syncthreads();

    __bf16* myy = ytile + w * 16 * CPITCH;

    #pragma unroll
    for (int t2 = 0; t2 < 2; ++t2) {
        const int bt = t2 * 64 + w * 16;

        f32x4 acc[12];
        chk_layer1(wlds, l, bA[t2], bB[t2], acc);

        f32x4 acc2[3];
        chk_layer2g(wl2, l, q, acc, acc2);

        #pragma unroll
        for (int mt = 0; mt < 3; ++mt)
            #pragma unroll
            for (int r = 0; r < 4; ++r)
                myy[c * CPITCH + mt * 16 + q * 4 + r] = (__bf16)(acc2[mt][r] * sg[t2]);
        wave_lds_fence();

        {
            int s = l >> 4, row = l & 15;
            u32x4 vv = *(const u32x4*)(myy + row * CPITCH + s * 8);
            *(u32x4*)(c2v + ((size_t)(m * 6 + s) * BB + bt + row) * 8) = vv;
            if (l < 32) {
                int s2 = 4 + (l >> 4), row2 = l & 15;
                u32x4 v2 = *(const u32x4*)(myy + row2 * CPITCH + s2 * 8);
                *(u32x4*)(c2v + ((size_t)(m * 6 + s2) * BB + bt + row2) * 8) = v2;
            }
        }
        wave_lds_fence();
    }
}

__device__ __forceinline__ void var_stage4(const __bf16* __restrict__ wvar,
                                           int nv, int tid, __bf16* buf)
{
    const __bf16* src = wvar + (size_t)nv * VAR_W_ELEMS;
    #pragma unroll
    for (int r = 0; r < 3; ++r)
        __builtin_amdgcn_global_load_lds(
            (gas_p)(src + (r * 256 + tid) * 8),
            (las_p)(buf + (r * 256 + tid) * 8), 16, 0, 0);
    if (tid < 128)
        __builtin_amdgcn_global_load_lds(
            (gas_p)(src + (768 + tid) * 8),
            (las_p)(buf + (768 + tid) * 8), 16, 0, 0);
}

// one var-MLP task body (math identical to r6)
__device__ __forceinline__ void var_compute(
    const __bf16* buf, const bf16x8* bp, int nv,
    int w, int l, int q, int c, int last,
    __bf16* myy, __bf16* __restrict__ v2c, float* __restrict__ llr_out)
{
    #pragma unroll
    for (int t2 = 0; t2 < 2; ++t2) {
        const int bt = t2 * 64 + w * 16;
        const bf16x8 b0 = bp[t2];

        f32x4 acc[7];
        #pragma unroll
        for (int mt = 0; mt < 7; ++mt) {
            bf16x8 a0 = *(const bf16x8*)(buf + mt * 512 + l * 8);
            f32x4 z = {0.f, 0.f, 0.f, 0.f};
            acc[mt] = __builtin_amdgcn_mfma_f32_16x16x32_bf16(a0, b0, z, 0, 0, 0);
        }

        f32x4 acc2[2];
        acc2[0] = (f32x4){0.f, 0.f, 0.f, 0.f};
        acc2[1] = (f32x4){0.f, 0.f, 0.f, 0.f};
        #pragma unroll
        for (int kp = 0; kp < 3; ++kp) {
            bf16x4 bf0, bf1;
            #pragma unroll
            for (int r = 0; r < 4; ++r) bf0[r] = (__bf16)gelu_fast(acc[2 * kp][r]);
            #pragma unroll
            for (int r = 0; r < 4; ++r) bf1[r] = (__bf16)gelu_fast(acc[2 * kp + 1][r]);
            #pragma unroll
            for (int mt = 0; mt < 2; ++mt) {
                bf16x8 a8 = *(const bf16x8*)(buf + VAR_L2_OFF + mt * 1792 + kp * 512 + l * 8);
                bf16x4 alo = {a8[0], a8[1], a8[2], a8[3]};
                bf16x4 ahi = {a8[4], a8[5], a8[6], a8[7]};
                acc2[mt] = mfma16(alo, bf0, acc2[mt]);
                acc2[mt] = mfma16(ahi, bf1, acc2[mt]);
            }
        }
        {
            bf16x4 bf6;
            #pragma unroll
            for (int r = 0; r < 4; ++r) bf6[r] = (__bf16)gelu_fast(acc[6][r]);
            if (q == 1) bf6[0] = (__bf16)1.0f;
            #pragma unroll
            for (int mt = 0; mt < 2; ++mt) {
                bf16x4 af = *(const bf16x4*)(buf + VAR_L2_OFF + mt * 1792 + 1536 + l * 4);
                acc2[mt] = mfma16(af, bf6, acc2[mt]);
            }
        }

        #pragma unroll
        for (int r = 0; r < 4; ++r)
            myy[c * VPITCH + q * 4 + r] = (__bf16)acc2[0][r];
        if (q < 2)
            #pragma unroll
            for (int r = 0; r < 4; ++r)
                myy[c * VPITCH + 16 + q * 4 + r] = (__bf16)acc2[1][r];
        if (q == 2) llr_out[(size_t)(bt + c) * NN + nv] = acc2[1][0];
        wave_lds_fence();

        if (!last && l < 48) {
            int s = l >> 4, row = l & 15;
            u32x4 vv = *(const u32x4*)(myy + row * VPITCH + s * 8);
            *(u32x4*)(v2c + ((size_t)(nv * 3 + s) * BB + bt + row) * 8) = vv;
        }
        wave_lds_fence();
    }
}

// ---------------------------------------------------------------------------
// Variable MLP r8: 2 nv per block, ping-pong LDS staging. Task-1 staging is
// issued BEFORE task-0 compute; counted vmcnt(4) releases task 0 while task
// 1's weights stay in flight (T14). 1024 blocks at 4/CU = single round.
// ---------------------------------------------------------------------------
__global__ __launch_bounds__(256, 4)
void var_kernel(const __bf16* __restrict__ wvar,
                const int* __restrict__ c2v_gather, const float* __restrict__ prior,
                const __bf16* __restrict__ c2v, __bf16* __restrict__ v2c,
                float* __restrict__ llr_out, int last)
{
    const int nv0 = blockIdx.x * 2;
    const int tid = threadIdx.x;
    const int w = tid >> 6, l = tid & 63, q = l >> 4, c = l & 15;

    __shared__ __align__(16) __bf16 wbuf[2 * VAR_W_ELEMS];  // 28.7 KB ping-pong
    __shared__ __align__(16) __bf16 ytile[4 * 16 * VPITCH]; // 3.25 KB

    // edge ids + priors for both tasks (issued before staging)
    int eps[2];
    float prs[2];
    #pragma unroll
    for (int j = 0; j < 2; ++j) {
        eps[j] = (q < 3) ? c2v_gather[(nv0 + j) * 3 + q] : 0;
        prs[j] = prior[nv0 + j];
    }

    // stage task 0
    var_stage4(wvar, nv0, tid, wbuf);

    // b-frags for task 0
    bf16x8 bp0[2];
    #pragma unroll
    for (int t2 = 0; t2 < 2; ++t2) {
        const int bt = t2 * 64 + w * 16;
        bf16x8 bb;
        #pragma unroll
        for (int j = 0; j < 8; ++j) bb[j] = (__bf16)0.0f;
        if (q < 3) bb = *(const bf16x8*)(c2v + ((size_t)eps[0] * BB + bt + c) * 8);
        else { bb[0] = (__bf16)prs[0]; bb[1] = (__bf16)1.0f; }
        bp0[t2] = bb;
    }
    __builtin_amdgcn_sched_barrier(0);

    // stage task 1 (stays in flight across task-0 compute)
    var_stage4(wvar, nv0 + 1, tid, wbuf + VAR_W_ELEMS);
    __builtin_amdgcn_sched_barrier(0);
    asm volatile("s_waitcnt vmcnt(4)" ::: "memory");   // task-0 stage + bfrags landed
    __syncthreads();

    __bf16* myy = ytile + w * 16 * VPITCH;

    var_compute(wbuf, bp0, nv0, w, l, q, c, last, myy, v2c, llr_out);

    // b-frags for task 1
    bf16x8 bp1[2];
    #pragma unroll
    for (int t2 = 0; t2 < 2; ++t2) {
        const int bt = t2 * 64 + w * 16;
        bf16x8 bb;
        #pragma unroll
        for (int j = 0; j < 8; ++j) bb[j] = (__bf16)0.0f;
        if (q < 3) bb = *(const bf16x8*)(c2v + ((size_t)eps[1] * BB + bt + c) * 8);
        else { bb[0] = (__bf16)prs[1]; bb[1] = (__bf16)1.0f; }
        bp1[t2] = bb;
    }
    __builtin_amdgcn_sched_barrier(0);
    asm volatile("s_waitcnt vmcnt(0)" ::: "memory");   // task-1 stage + bfrags landed
    __syncthreads();

    var_compute(wbuf + VAR_W_ELEMS, bp1, nv0 + 1, w, l, q, c, last,
                myy, v2c, llr_out);
}

extern "C" void kernel_launch(void* const* d_in, const int* in_sizes, int n_in,
                              void* d_out, int out_size, void* d_ws, size_t ws_size,
                              hipStream_t stream) {
    const int*   syndromes = (const int*)  d_in[0];
    const float* prior_llr = (const float*)d_in[1];
    const float* chk_w1    = (const float*)d_in[2];
    const float* chk_b1    = (const float*)d_in[3];
    const float* chk_w2    = (const float*)d_in[4];
    const float* chk_b2    = (const float*)d_in[5];
    const float* var_w1    = (const float*)d_in[6];
    const float* var_b1    = (const float*)d_in[7];
    const float* var_w2    = (const float*)d_in[8];
    const float* var_b2    = (const float*)d_in[9];
    const int*   c2v_g     = (const int*)  d_in[11];
    const int*   v2c_g     = (const int*)  d_in[12];

    float* out = (float*)d_out;

    __bf16* v2c  = (__bf16*)d_ws;                           // 12.6 MB
    __bf16* c2v  = v2c + (size_t)EE * BB * 8;               // 12.6 MB
    __bf16* wchk = c2v + (size_t)EE * BB * 8;               // 45.6 MB
    __bf16* wvar = wchk + (size_t)MM * CHK_W_ELEMS;         // 29.4 MB
    float*  sgnT = (float*)(wvar + (size_t)NN * VAR_W_ELEMS); // 512 KB

    prep_chk<<<MM, 256, 0, stream>>>(chk_w1, chk_b1, chk_w2, chk_b2, wchk);
    prep_other<<<PREP_OTHER_GRID, 256, 0, stream>>>(var_w1, var_b1, var_w2, var_b2,
                                                    syndromes, prior_llr,
                                                    wvar, sgnT, v2c);

    for (int t = 0; t < TT; ++t) {
        chk_kernel<<<MM, 256, 0, stream>>>(wchk, sgnT, v2c_g, v2c, c2v);
        var_kernel<<<NN / 2, 256, 0, stream>>>(wvar, c2v_g, prior_llr, c2v, v2c,
                                               out + (size_t)t * BB * NN,
                                               (t == TT - 1) ? 1 : 0);
    }
}

// Round 12
// 391.901 us; speedup vs baseline: 3.4407x; 1.1313x over previous
//
#include <hip/hip_runtime.h>
#include <math.h>

#define MM 1024      // checks
#define NN 2048      // vars
#define BB 128       // batch
#define TT 5         // iterations
#define EE 6144      // edges

typedef __bf16 bf16x8 __attribute__((ext_vector_type(8)));
typedef __bf16 bf16x4 __attribute__((ext_vector_type(4)));
typedef short  s16x4  __attribute__((ext_vector_type(4)));
typedef float  f32x4  __attribute__((ext_vector_type(4)));
typedef unsigned int u32x4 __attribute__((ext_vector_type(4)));

typedef const __attribute__((address_space(1))) void* gas_p;
typedef __attribute__((address_space(3))) void* las_p;

// prepped weight sizes (bf16 elements), r4 ORIGINAL layout
#define CHK_W_ELEMS 22272   // 24 x32-frags (512) + 39 x16-frags (256)
#define CHK_L2_OFF  12288
#define VAR_W_ELEMS 7168    // 7 x32-frags + 14 x16-frags
#define VAR_L2_OFF  3584

// Abramowitz-Stegun 7.1.26 erf (|eps| < 1.5e-7)
__device__ __forceinline__ float gelu_fast(float x) {
    float xe = x * 0.70710678118654752f;
    float ax = fabsf(xe);
    float t  = __builtin_amdgcn_rcpf(1.0f + 0.3275911f * ax);
    float p  = t * (0.254829592f + t * (-0.284496736f + t * (1.421413741f +
               t * (-1.453152027f + t * 1.061405429f))));
    float er = 1.0f - p * __expf(-xe * xe);
    er = copysignf(er, xe);
    return 0.5f * x * (1.0f + er);
}

__device__ __forceinline__ f32x4 mfma16(bf16x4 a, bf16x4 b, f32x4 c) {
#if __has_builtin(__builtin_amdgcn_mfma_f32_16x16x16bf16_1k)
    return __builtin_amdgcn_mfma_f32_16x16x16bf16_1k(
        __builtin_bit_cast(s16x4, a), __builtin_bit_cast(s16x4, b), c, 0, 0, 0);
#else
    f32x4 d;
    asm volatile("v_mfma_f32_16x16x16_bf16 %0, %1, %2, %3\n\ts_nop 4"
                 : "=v"(d) : "v"(a), "v"(b), "v"(c));
    return d;
#endif
}

// wave-private LDS fence (DS ops in-order per wave)
__device__ __forceinline__ void wave_lds_fence() {
    asm volatile("s_waitcnt lgkmcnt(0)" ::: "memory");
}

// ---------------------------------------------------------------------------
// prep: r3 barrier-free wave-private packing, split in two (neither dispatch
// tops the loop kernels -> rocprof top-5 shows loop work). Emission layout =
// r4 ORIGINAL (non-interleaved) to match the proven loop kernels.
// ---------------------------------------------------------------------------
__global__ __launch_bounds__(256, 6)
void prep_chk(const float* __restrict__ cw1, const float* __restrict__ cb1,
              const float* __restrict__ cw2, const float* __restrict__ cb2,
              __bf16* __restrict__ wchk)
{
    const int tid = threadIdx.x;
    const int w = tid >> 6, l = tid & 63, q = l >> 4, c = l & 15;

    __shared__ __align__(16) float s[6656];
    float* sw = s + w * 1664;

    const int m = blockIdx.x;
    const float* w1p = cw1 + (size_t)m * 9216;
    const float* w2p = cw2 + (size_t)m * 9216;
    __bf16* dst = wchk + (size_t)m * CHK_W_ELEMS;

    // ---- w1, col slice [48w, 48w+48), kt=0 (rows 0..31); pitch 50 ----
    #pragma unroll
    for (int i0 = 0; i0 < 6; ++i0) {
        int i = i0 * 64 + l;
        int r = i / 12, c4 = i % 12;
        float4 v = *(const float4*)(w1p + r * 192 + w * 48 + c4 * 4);
        *(float2*)(sw + r * 50 + c4 * 4)     = make_float2(v.x, v.y);
        *(float2*)(sw + r * 50 + c4 * 4 + 2) = make_float2(v.z, v.w);
    }
    wave_lds_fence();
    #pragma unroll
    for (int d = 0; d < 3; ++d) {
        int mt = 3 * w + d;
        bf16x8 v;
        #pragma unroll
        for (int j = 0; j < 8; ++j)
            v[j] = (__bf16)sw[(q * 8 + j) * 50 + d * 16 + c];
        *(bf16x8*)(dst + (mt * 2) * 512 + l * 8) = v;
    }
    wave_lds_fence();

    // ---- w1 kt=1 (rows 32..47 local 0..15, bias row 16) ----
    #pragma unroll
    for (int i0 = 0; i0 < 4; ++i0) {
        int i = i0 * 64 + l;
        if (i < 204) {
            int r = i / 12, c4 = i % 12;
            const float* src = (r < 16)
                ? (w1p + (32 + r) * 192 + w * 48 + c4 * 4)
                : (cb1 + (size_t)m * 192 + w * 48 + c4 * 4);
            float4 v = *(const float4*)src;
            *(float2*)(sw + r * 50 + c4 * 4)     = make_float2(v.x, v.y);
            *(float2*)(sw + r * 50 + c4 * 4 + 2) = make_float2(v.z, v.w);
        }
    }
    wave_lds_fence();
    #pragma unroll
    for (int d = 0; d < 3; ++d) {
        int mt = 3 * w + d;
        bf16x8 v;
        #pragma unroll
        for (int j = 0; j < 8; ++j) {
            int lr = q * 8 + j;                  // k = 32 + lr
            float wv = sw[lr * 50 + d * 16 + c]; // in-bounds garbage ok
            v[j] = (__bf16)((lr <= 16) ? wv : 0.0f);
        }
        *(bf16x8*)(dst + (mt * 2 + 1) * 512 + l * 8) = v;
    }
    wave_lds_fence();

    // ---- w2 tasks: t in 0..8 = (kb,mt) tiles; t=9 = ks12 bias frags ----
    for (int t = w; t < 10; t += 4) {
        if (t < 9) {
            const int kb = t / 3, mt = t - kb * 3;
            #pragma unroll
            for (int i0 = 0; i0 < 4; ++i0) {
                int i = i0 * 64 + l;
                int r = i >> 2, c4 = i & 3;
                float4 v = *(const float4*)(w2p + (kb * 64 + r) * 48 + mt * 16 + c4 * 4);
                *(float4*)(sw + r * 20 + c4 * 4) = v;
            }
            wave_lds_fence();
            #pragma unroll
            for (int kk = 0; kk < 4; ++kk) {
                bf16x4 v;
                #pragma unroll
                for (int r = 0; r < 4; ++r)
                    v[r] = (__bf16)sw[(kk * 16 + q * 4 + r) * 20 + c];
                *(bf16x4*)(dst + CHK_L2_OFF + ((kb * 4 + kk) * 3 + mt) * 256 + l * 4) = v;
            }
            wave_lds_fence();
        } else {
            // ks = 12: only k==192 (q==0, r==0) is the bias row
            #pragma unroll
            for (int mt = 0; mt < 3; ++mt) {
                bf16x4 v;
                #pragma unroll
                for (int r = 0; r < 4; ++r) v[r] = (__bf16)0.0f;
                if (q == 0) v[0] = (__bf16)cb2[(size_t)m * 48 + mt * 16 + c];
                *(bf16x4*)(dst + CHK_L2_OFF + (36 + mt) * 256 + l * 4) = v;
            }
        }
    }
}

#define PREP_OTHER_GRID (2048 + 512 + 3072)

__global__ __launch_bounds__(256, 6)
void prep_other(const float* __restrict__ vw1, const float* __restrict__ vb1,
                const float* __restrict__ vw2, const float* __restrict__ vb2,
                const int* __restrict__ synd, const float* __restrict__ prior,
                __bf16* __restrict__ wvar, float* __restrict__ sgnT,
                __bf16* __restrict__ v2c)
{
    const int bid = blockIdx.x;
    const int tid = threadIdx.x;
    const int w = tid >> 6, l = tid & 63, q = l >> 4, c = l & 15;

    __shared__ __align__(16) float s[6656];
    float* sw = s + w * 1664;

    if (bid < 2048) {
        const int nv = bid;
        const float* w1p = vw1 + (size_t)nv * 2500;
        const float* w2p = vw2 + (size_t)nv * 2500;
        __bf16* dst = wvar + (size_t)nv * VAR_W_ELEMS;

        if (w < 3) {
            #pragma unroll
            for (int i0 = 0; i0 < 4; ++i0) {
                int i = i0 * 64 + l;
                if (i < 208) {
                    int r = i >> 3, c4 = i & 7;
                    const float* src = (r < 25)
                        ? (w1p + r * 100 + w * 32 + c4 * 4)
                        : (vb1 + (size_t)nv * 100 + w * 32 + c4 * 4);
                    float4 v = *(const float4*)src;
                    *(float2*)(sw + r * 34 + c4 * 4)     = make_float2(v.x, v.y);
                    *(float2*)(sw + r * 34 + c4 * 4 + 2) = make_float2(v.z, v.w);
                }
            }
        } else {
            if (l < 26) {
                int r = l;
                const float* src = (r < 25) ? (w1p + r * 100 + 96)
                                            : (vb1 + (size_t)nv * 100 + 96);
                float4 v = *(const float4*)src;
                *(float2*)(sw + r * 34)     = make_float2(v.x, v.y);
                *(float2*)(sw + r * 34 + 2) = make_float2(v.z, v.w);
            }
        }
        wave_lds_fence();
        {
            const int nmt = (w < 3) ? 2 : 1;
            #pragma unroll
            for (int d = 0; d < 2; ++d) {
                if (d < nmt) {
                    const int mt = (w < 3) ? (2 * w + d) : 6;
                    const int h = mt * 16 + c;
                    bf16x8 v;
                    #pragma unroll
                    for (int j = 0; j < 8; ++j) {
                        int k = q * 8 + j;
                        float wv = sw[k * 34 + d * 16 + c];   // in-bounds garbage ok
                        v[j] = (__bf16)((h < 100 && k <= 25) ? wv : 0.0f);
                    }
                    *(bf16x8*)(dst + mt * 512 + l * 8) = v;
                }
            }
        }
        wave_lds_fence();

        if (w < 3) {
            #pragma unroll
            for (int i0 = 0; i0 < 4; ++i0) {
                int i = i0 * 64 + l;
                if (i < 200)
                    *(float4*)(sw + i * 4) = *(const float4*)(w2p + 800 * w + i * 4);
            }
        } else {
            if (l < 25) *(float4*)(sw + l * 4) = *(const float4*)(w2p + 2400 + l * 4);
            if (l < 25) sw[100 + l] = vb2[(size_t)nv * 25 + l];
        }
        wave_lds_fence();
        {
            const int nks = (w < 3) ? 2 : 1;
            #pragma unroll
            for (int kk = 0; kk < 2; ++kk) {
                if (kk < nks) {
                    const int ks = (w < 3) ? (2 * w + kk) : 6;
                    #pragma unroll
                    for (int mt = 0; mt < 2; ++mt) {
                        const int o = mt * 16 + c;
                        bf16x4 v;
                        #pragma unroll
                        for (int r = 0; r < 4; ++r) {
                            float x;
                            if (w < 3) {
                                int lk = kk * 16 + q * 4 + r;     // k=32w+lk <= 95 < 100
                                float wv = sw[lk * 25 + o];
                                x = (o < 25) ? wv : 0.0f;
                            } else {
                                int lk = q * 4 + r;               // k = 96+lk; lk==4 -> bias
                                float wv = sw[lk * 25 + o];
                                x = (o < 25 && lk <= 4) ? wv : 0.0f;
                            }
                            v[r] = (__bf16)x;
                        }
                        *(bf16x4*)(dst + VAR_L2_OFF + (ks * 2 + mt) * 256 + l * 4) = v;
                    }
                }
            }
        }
    } else if (bid < 2560) {
        int idx = (bid - 2048) * 256 + tid;        // m*128 + b
        int m = idx >> 7, b = idx & 127;
        sgnT[idx] = (float)(1 - 2 * synd[(size_t)b * MM + m]);
    } else {
        int idx = (bid - 2560) * 256 + tid;
        int e = idx >> 7;
        bf16x8 v;
        #pragma unroll
        for (int j = 0; j < 8; ++j) v[j] = (__bf16)0.0f;
        v[0] = (__bf16)prior[e / 3];
        *(bf16x8*)(v2c + (size_t)idx * 8) = v;
    }
}

// ---------------------------------------------------------------------------
// chk layer helpers (r4 exact)
// ---------------------------------------------------------------------------
__device__ __forceinline__ void chk_layer1(const __bf16* wlds, int l,
                                           bf16x8 b0, bf16x8 b1, f32x4* acc)
{
    #pragma unroll
    for (int mt = 0; mt < 12; ++mt) {
        bf16x8 a0 = *(const bf16x8*)(wlds + (mt * 2 + 0) * 512 + l * 8);
        bf16x8 a1 = *(const bf16x8*)(wlds + (mt * 2 + 1) * 512 + l * 8);
        f32x4 z = {0.f, 0.f, 0.f, 0.f};
        z = __builtin_amdgcn_mfma_f32_16x16x32_bf16(a0, b0, z, 0, 0, 0);
        z = __builtin_amdgcn_mfma_f32_16x16x32_bf16(a1, b1, z, 0, 0, 0);
        acc[mt] = z;
    }
}

__device__ __forceinline__ void chk_layer2(const __bf16* wlds, int l, int q,
                                           const f32x4* acc, f32x4* acc2)
{
    #pragma unroll
    for (int mt = 0; mt < 3; ++mt) acc2[mt] = (f32x4){0.f, 0.f, 0.f, 0.f};
    #pragma unroll
    for (int ks = 0; ks < 13; ++ks) {
        bf16x4 bf;
        if (ks < 12) {
            #pragma unroll
            for (int r = 0; r < 4; ++r) bf[r] = (__bf16)gelu_fast(acc[ks][r]);
        } else {
            #pragma unroll
            for (int r = 0; r < 4; ++r) bf[r] = (__bf16)0.0f;
            if (q == 0) bf[0] = (__bf16)1.0f;   // k=192 bias row
        }
        #pragma unroll
        for (int mt = 0; mt < 3; ++mt) {
            bf16x4 af = *(const bf16x4*)(wlds + CHK_L2_OFF + (ks * 3 + mt) * 256 + l * 4);
            acc2[mt] = mfma16(af, bf, acc2[mt]);
        }
    }
}

// ---------------------------------------------------------------------------
// Check MLP = r4 exact (best measured): gload_lds two-phase staging,
// b-frag/sign prefetch, vmcnt(5) releases layer1 while layer2 streams in.
// ---------------------------------------------------------------------------
#define CPITCH 58   // Y tile pitch (elements); 29c mod 32 spreads banks
__global__ __launch_bounds__(256, 3)
void chk_kernel(const __bf16* __restrict__ wchk,
                const float* __restrict__ sgnT,
                const int* __restrict__ v2c_gather,
                const __bf16* __restrict__ v2c, __bf16* __restrict__ c2v)
{
    const int m = blockIdx.x;
    const int tid = threadIdx.x;
    const int w = tid >> 6, l = tid & 63, q = l >> 4, c = l & 15;

    __shared__ __align__(16) __bf16 wlds[CHK_W_ELEMS];      // 43.5 KB
    __shared__ __align__(16) __bf16 ytile[4 * 16 * CPITCH]; // 7.25 KB

    // edge ids first
    const int e0 = v2c_gather[m * 6 + q];
    const int e1 = (q < 2) ? v2c_gather[m * 6 + 4 + q] : 0;

    // prefetch B-frags + signs for both t2 halves
    bf16x8 bA[2], bB[2];
    float sg[2];
    #pragma unroll
    for (int t2 = 0; t2 < 2; ++t2) {
        const int bt = t2 * 64 + w * 16;
        bA[t2] = *(const bf16x8*)(v2c + ((size_t)e0 * BB + bt + c) * 8);
        bf16x8 bb;
        #pragma unroll
        for (int j = 0; j < 8; ++j) bb[j] = (__bf16)0.0f;
        if (q < 2)       bb = *(const bf16x8*)(v2c + ((size_t)e1 * BB + bt + c) * 8);
        else if (q == 2) bb[0] = (__bf16)1.0f;   // bias row k=48
        bB[t2] = bb;
        sg[t2] = sgnT[m * BB + bt + c];
    }

    // stage weights: 11 gload_lds rounds of 4KB (last partial: 224 chunks)
    {
        const __bf16* src = wchk + (size_t)m * CHK_W_ELEMS;
        #pragma unroll
        for (int r = 0; r < 10; ++r)
            __builtin_amdgcn_global_load_lds(
                (gas_p)(src + (r * 256 + tid) * 8),
                (las_p)(wlds + (r * 256 + tid) * 8), 16, 0, 0);
        if (tid < 224)
            __builtin_amdgcn_global_load_lds(
                (gas_p)(src + (2560 + tid) * 8),
                (las_p)(wlds + (2560 + tid) * 8), 16, 0, 0);
    }
    __builtin_amdgcn_sched_barrier(0);
    asm volatile("s_waitcnt vmcnt(5)" ::: "memory");   // L1 rounds 0-5 landed
    __syncthreads();

    __bf16* myy = ytile + w * 16 * CPITCH;   // [batch 16][out 48], wave-private

    // ---- t2=0 layer1 (only L1 region) while L2 weights stream in ----
    f32x4 acc[12];
    chk_layer1(wlds, l, bA[0], bB[0], acc);

    __builtin_amdgcn_sched_barrier(0);
    asm volatile("s_waitcnt vmcnt(0)" ::: "memory");   // L2 rounds landed
    __syncthreads();

    #pragma unroll
    for (int t2 = 0; t2 < 2; ++t2) {
        if (t2 == 1) chk_layer1(wlds, l, bA[1], bB[1], acc);
        const int bt = t2 * 64 + w * 16;

        f32x4 acc2[3];
        chk_layer2(wlds, l, q, acc, acc2);

        // epilogue: sign + transpose via wave-private LDS tile [b][o]
        #pragma unroll
        for (int mt = 0; mt < 3; ++mt)
            #pragma unroll
            for (int r = 0; r < 4; ++r)
                myy[c * CPITCH + mt * 16 + q * 4 + r] = (__bf16)(acc2[mt][r] * sg[t2]);
        wave_lds_fence();

        // coalesced 16B chunk stores: (slot s, row) -> c2v[e=m*6+s][bt+row][0..7]
        {
            int s = l >> 4, row = l & 15;
            u32x4 vv = *(const u32x4*)(myy + row * CPITCH + s * 8);
            *(u32x4*)(c2v + ((size_t)(m * 6 + s) * BB + bt + row) * 8) = vv;
            if (l < 32) {
                int s2 = 4 + (l >> 4), row2 = l & 15;
                u32x4 v2 = *(const u32x4*)(myy + row2 * CPITCH + s2 * 8);
                *(u32x4*)(c2v + ((size_t)(m * 6 + s2) * BB + bt + row2) * 8) = v2;
            }
        }
        wave_lds_fence();   // reads done before next-t2 tile writes
    }
}

// ---------------------------------------------------------------------------
// Variable MLP = r4 structure; single experimental delta: occupancy 5->6
// blocks/CU (LDS 17.5 KB x 6 = 105 KB fits; VGPR cap ~85). 2048 blocks:
// 1.6 rounds @5/CU -> 1.33 rounds @6/CU, cutting the second-round tail.
// ---------------------------------------------------------------------------
#define VPITCH 26
__global__ __launch_bounds__(256, 6)
void var_kernel(const __bf16* __restrict__ wvar,
                const int* __restrict__ c2v_gather, const float* __restrict__ prior,
                const __bf16* __restrict__ c2v, __bf16* __restrict__ v2c,
                float* __restrict__ llr_out, int last)
{
    const int nv = blockIdx.x;
    const int tid = threadIdx.x;
    const int w = tid >> 6, l = tid & 63, q = l >> 4, c = l & 15;

    __shared__ __align__(16) __bf16 wlds[VAR_W_ELEMS];      // 14.3 KB
    __shared__ __align__(16) __bf16 ytile[4 * 16 * VPITCH]; // 3.25 KB

    const int ep = (q < 3) ? c2v_gather[nv * 3 + q] : 0;
    const __bf16 prbf = (__bf16)prior[nv];

    // prefetch both t2 B-frags
    bf16x8 bp[2];
    #pragma unroll
    for (int t2 = 0; t2 < 2; ++t2) {
        const int bt = t2 * 64 + w * 16;
        bf16x8 bb;
        #pragma unroll
        for (int j = 0; j < 8; ++j) bb[j] = (__bf16)0.0f;
        if (q < 3) bb = *(const bf16x8*)(c2v + ((size_t)ep * BB + bt + c) * 8);
        else { bb[0] = prbf; bb[1] = (__bf16)1.0f; }   // k=24 prior, k=25 bias
        bp[t2] = bb;
    }

    // stage weights: 3 full rounds + 1 partial (128 chunks)
    {
        const __bf16* src = wvar + (size_t)nv * VAR_W_ELEMS;
        #pragma unroll
        for (int r = 0; r < 3; ++r)
            __builtin_amdgcn_global_load_lds(
                (gas_p)(src + (r * 256 + tid) * 8),
                (las_p)(wlds + (r * 256 + tid) * 8), 16, 0, 0);
        if (tid < 128)
            __builtin_amdgcn_global_load_lds(
                (gas_p)(src + (768 + tid) * 8),
                (las_p)(wlds + (768 + tid) * 8), 16, 0, 0);
    }
    __builtin_amdgcn_sched_barrier(0);
    asm volatile("s_waitcnt vmcnt(0)" ::: "memory");
    __syncthreads();

    __bf16* myy = ytile + w * 16 * VPITCH;   // [batch 16][out 24]

    #pragma unroll
    for (int t2 = 0; t2 < 2; ++t2) {
        const int bt = t2 * 64 + w * 16;
        const bf16x8 b0 = bp[t2];

        f32x4 acc[7];
        #pragma unroll
        for (int mt = 0; mt < 7; ++mt) {
            bf16x8 a0 = *(const bf16x8*)(wlds + mt * 512 + l * 8);
            f32x4 z = {0.f, 0.f, 0.f, 0.f};
            acc[mt] = __builtin_amdgcn_mfma_f32_16x16x32_bf16(a0, b0, z, 0, 0, 0);
        }

        f32x4 acc2[2];
        acc2[0] = (f32x4){0.f, 0.f, 0.f, 0.f};
        acc2[1] = (f32x4){0.f, 0.f, 0.f, 0.f};
        #pragma unroll
        for (int ks = 0; ks < 7; ++ks) {
            bf16x4 bf;
            #pragma unroll
            for (int r = 0; r < 4; ++r) bf[r] = (__bf16)gelu_fast(acc[ks][r]);
            if (ks == 6 && q == 1) bf[0] = (__bf16)1.0f;   // k=100 bias row
            #pragma unroll
            for (int mt = 0; mt < 2; ++mt) {
                bf16x4 af = *(const bf16x4*)(wlds + VAR_L2_OFF + (ks * 2 + mt) * 256 + l * 4);
                acc2[mt] = mfma16(af, bf, acc2[mt]);
            }
        }

        // epilogue: messages (o<24) via LDS tile; LLR (o=24) f32 direct
        #pragma unroll
        for (int r = 0; r < 4; ++r)
            myy[c * VPITCH + q * 4 + r] = (__bf16)acc2[0][r];
        if (q < 2)
            #pragma unroll
            for (int r = 0; r < 4; ++r)
                myy[c * VPITCH + 16 + q * 4 + r] = (__bf16)acc2[1][r];
        if (q == 2) llr_out[(size_t)(bt + c) * NN + nv] = acc2[1][0];
        wave_lds_fence();

        if (!last && l < 48) {
            int s = l >> 4, row = l & 15;
            u32x4 vv = *(const u32x4*)(myy + row * VPITCH + s * 8);
            *(u32x4*)(v2c + ((size_t)(nv * 3 + s) * BB + bt + row) * 8) = vv;
        }
        wave_lds_fence();
    }
}

extern "C" void kernel_launch(void* const* d_in, const int* in_sizes, int n_in,
                              void* d_out, int out_size, void* d_ws, size_t ws_size,
                              hipStream_t stream) {
    const int*   syndromes = (const int*)  d_in[0];
    const float* prior_llr = (const float*)d_in[1];
    const float* chk_w1    = (const float*)d_in[2];
    const float* chk_b1    = (const float*)d_in[3];
    const float* chk_w2    = (const float*)d_in[4];
    const float* chk_b2    = (const float*)d_in[5];
    const float* var_w1    = (const float*)d_in[6];
    const float* var_b1    = (const float*)d_in[7];
    const float* var_w2    = (const float*)d_in[8];
    const float* var_b2    = (const float*)d_in[9];
    const int*   c2v_g     = (const int*)  d_in[11];
    const int*   v2c_g     = (const int*)  d_in[12];

    float* out = (float*)d_out;

    __bf16* v2c  = (__bf16*)d_ws;                           // 12.6 MB
    __bf16* c2v  = v2c + (size_t)EE * BB * 8;               // 12.6 MB
    __bf16* wchk = c2v + (size_t)EE * BB * 8;               // 45.6 MB
    __bf16* wvar = wchk + (size_t)MM * CHK_W_ELEMS;         // 29.4 MB
    float*  sgnT = (float*)(wvar + (size_t)NN * VAR_W_ELEMS); // 512 KB

    prep_chk<<<MM, 256, 0, stream>>>(chk_w1, chk_b1, chk_w2, chk_b2, wchk);
    prep_other<<<PREP_OTHER_GRID, 256, 0, stream>>>(var_w1, var_b1, var_w2, var_b2,
                                                    syndromes, prior_llr,
                                                    wvar, sgnT, v2c);

    for (int t = 0; t < TT; ++t) {
        chk_kernel<<<MM, 256, 0, stream>>>(wchk, sgnT, v2c_g, v2c, c2v);
        var_kernel<<<NN, 256, 0, stream>>>(wvar, c2v_g, prior_llr, c2v, v2c,
                                           out + (size_t)t * BB * NN,
                                           (t == TT - 1) ? 1 : 0);
    }
}